// Round 5
// baseline (755.798 us; speedup 1.0000x reference)
//
#include <hip/hip_runtime.h>

#define B_ 128
#define T_ 2048
#define K_ 64
#define NF_ 256
#define L2E 1.44269504088896340736f
#define LN2 0.69314718055994530942f

__device__ __forceinline__ float rfl_f(float x) {
    return __int_as_float(__builtin_amdgcn_readfirstlane(__float_as_int(x)));
}
__device__ __forceinline__ float rdl_f(float x, int i) {
    return __int_as_float(__builtin_amdgcn_readlane(__float_as_int(x), i));
}

// Blocks [0, B_): one wave per batch element, CRF forward scan + gold score.
//   Exp-domain recurrence: aexp[j] ~ exp(alpha[j] - lognorm).
//   Step: aexp'[j] = (sum_i aexp[i] * W[i][j]) * exp(em_t[j]);  W = exp(trans).
//   Renorm by lane-0 value every 4 steps; lognorm accumulates the log.
// Blocks [B_, B_+NF_): focal-scale partial sums (data-parallel).
__global__ __launch_bounds__(64) void fcrf_main(
    const float* __restrict__ em, const int* __restrict__ lab,
    const int* __restrict__ msk, const float* __restrict__ trans,
    const float* __restrict__ stv, const float* __restrict__ env,
    float* __restrict__ ws)
{
    __shared__ float trans_sh[K_ * K_];
    const int lane = threadIdx.x;
    const int blk = blockIdx.x;

    if (blk < B_) {
        // ---------------- CRF scan path ----------------
        const int b = blk;
        const float* emb = em + (size_t)b * T_ * K_;
        const int* labb = lab + (size_t)b * T_;
        const int* mb = msk + (size_t)b * T_;

        // Lane j holds column j of W = exp(trans): w[i] = exp(trans[i][j]).
        float w[K_];
        #pragma unroll
        for (int i = 0; i < K_; ++i) {
            float tv = trans[i * K_ + lane];
            trans_sh[i * K_ + lane] = tv;   // raw trans for gold-path score
            w[i] = __builtin_amdgcn_exp2f(tv * L2E);
        }
        float endv = env[lane];
        float alpha0 = stv[lane] + emb[lane];   // log-domain init
        __syncthreads();  // one-time; trans_sh ready before loop

        float lognorm = rfl_f(alpha0);
        float aexp = __builtin_amdgcn_exp2f((alpha0 - lognorm) * L2E);

        int tag0 = labb[0];
        tag0 = (tag0 == -100) ? 0 : tag0;
        float sc = (lane == tag0) ? alpha0 : 0.f;  // start[tag0] + em[0,tag0]
        int ptag = tag0;

        // Prefetch pipeline: groups of 4 steps, loads issued one group ahead.
        float emc[4], emn[4];
        int tgc[4], tgn[4], mc[4], mn[4];
        #pragma unroll
        for (int j = 0; j < 4; ++j) {
            int t = 1 + j;
            emc[j] = emb[t * K_ + lane];
            int lb = labb[t];
            mc[j] = (lb != -100) & (mb[t] != 0);
            tgc[j] = (lb == -100) ? 0 : lb;
        }

        // Steps t = 1 .. 2048 (t=2048 is mask-forced to no-op); 512 groups of 4.
        for (int g = 0; g < 512; ++g) {
            // ---- prefetch next group (HBM latency hidden under this group) ----
            #pragma unroll
            for (int j = 0; j < 4; ++j) {
                int t = 1 + 4 * (g + 1) + j;
                int valid = (t < T_) ? 1 : 0;
                int tl = valid ? t : (T_ - 1);       // clamp: stay in-bounds
                emn[j] = emb[tl * K_ + lane];
                int lb = labb[tl];
                mn[j] = valid & (lb != -100) & (mb[tl] != 0);
                tgn[j] = (lb == -100) ? 0 : lb;
            }
            // ---- off-chain per-group prep: exp(em), gold ds_reads, ptag chain ----
            float dc[4], tvb[4];
            {
                int pt = ptag;
                #pragma unroll
                for (int j = 0; j < 4; ++j) {
                    dc[j] = __builtin_amdgcn_exp2f(emc[j] * L2E);
                    tvb[j] = trans_sh[pt * K_ + lane];   // issued early, used late
                    pt = mc[j] ? tgc[j] : pt;
                }
            }
            // ---- 4 serial scan steps (alpha critical path) ----
            #pragma unroll
            for (int j = 0; j < 4; ++j) {
                float a0 = 0.f, a1 = 0.f, a2 = 0.f, a3 = 0.f;
                #pragma unroll
                for (int i = 0; i < K_; i += 4) {
                    a0 = fmaf(rdl_f(aexp, i + 0), w[i + 0], a0);
                    a1 = fmaf(rdl_f(aexp, i + 1), w[i + 1], a1);
                    a2 = fmaf(rdl_f(aexp, i + 2), w[i + 2], a2);
                    a3 = fmaf(rdl_f(aexp, i + 3), w[i + 3], a3);
                }
                float nxt = ((a0 + a1) + (a2 + a3)) * dc[j];
                bool m = (mc[j] != 0);
                aexp = m ? nxt : aexp;
                // gold-path score (independent of alpha chain)
                int tg = tgc[j];
                float add = (lane == tg) ? (emc[j] + tvb[j]) : 0.f;
                sc += m ? add : 0.f;
                ptag = m ? tg : ptag;
            }
            // ---- renorm once per group ----
            {
                float sN = rfl_f(aexp);
                float rN = __builtin_amdgcn_rcpf(sN);
                aexp *= rN;
                lognorm = fmaf(__builtin_amdgcn_logf(sN), LN2, lognorm);
            }
            #pragma unroll
            for (int j = 0; j < 4; ++j) { emc[j] = emn[j]; tgc[j] = tgn[j]; mc[j] = mn[j]; }
        }

        // end contributions
        sc += (lane == ptag) ? endv : 0.f;
        #pragma unroll
        for (int off = 1; off < 64; off <<= 1) sc += __shfl_xor(sc, off, 64);

        // logZ = lognorm + log( sum_j aexp[j] * exp(end[j]) )
        float x = aexp * __builtin_amdgcn_exp2f(endv * L2E);
        #pragma unroll
        for (int off = 1; off < 64; off <<= 1) x += __shfl_xor(x, off, 64);
        float logZ = fmaf(__builtin_amdgcn_logf(x), LN2, lognorm);

        if (lane == 0) ws[b] = sc - logZ;   // llh_b
    } else {
        // ---------------- focal-scale path ----------------
        const int fb = blk - B_;
        const float4* em4 = (const float4*)em;
        const int sub = lane >> 4;       // which of 4 rows
        const int cg = lane & 15;        // 16 lanes cover one row (4 cols each)
        float facc = 0.f, cacc = 0.f;
        const int base = fb * (B_ * T_ / NF_);   // 1024 rows per block
        for (int it = 0; it < (B_ * T_ / NF_) / 4; ++it) {
            int row = base + it * 4 + sub;
            float4 v = em4[row * (K_ / 4) + cg];
            int lb = lab[row];
            int vm = (lb != -100) & (msk[row] != 0);
            int tg = (lb == -100) ? 0 : lb;
            float mx = fmaxf(fmaxf(v.x, v.y), fmaxf(v.z, v.w));
            #pragma unroll
            for (int off = 1; off < 16; off <<= 1) mx = fmaxf(mx, __shfl_xor(mx, off, 64));
            float se = __builtin_amdgcn_exp2f((v.x - mx) * L2E)
                     + __builtin_amdgcn_exp2f((v.y - mx) * L2E)
                     + __builtin_amdgcn_exp2f((v.z - mx) * L2E)
                     + __builtin_amdgcn_exp2f((v.w - mx) * L2E);
            int c0 = cg * 4;
            float sel = ((c0 + 0 == tg) ? v.x : 0.f) + ((c0 + 1 == tg) ? v.y : 0.f)
                      + ((c0 + 2 == tg) ? v.z : 0.f) + ((c0 + 3 == tg) ? v.w : 0.f);
            #pragma unroll
            for (int off = 1; off < 16; off <<= 1) {
                se += __shfl_xor(se, off, 64);
                sel += __shfl_xor(sel, off, 64);
            }
            float p = __builtin_amdgcn_exp2f((sel - mx) * L2E) / se;
            float fw = (1.f - p) * (1.f - p);
            if (cg == 0) {
                facc += vm ? fw : 0.f;
                cacc += vm ? 1.f : 0.f;
            }
        }
        #pragma unroll
        for (int off = 1; off < 64; off <<= 1) {
            facc += __shfl_xor(facc, off, 64);
            cacc += __shfl_xor(cacc, off, 64);
        }
        if (lane == 0) {
            ws[B_ + 2 * fb] = facc;
            ws[B_ + 2 * fb + 1] = cacc;
        }
    }
}

__global__ __launch_bounds__(64) void fcrf_final(const float* __restrict__ ws,
                                                 float* __restrict__ out)
{
    const int lane = threadIdx.x;
    float llh = ws[lane] + ws[64 + lane];
    float f = 0.f, c = 0.f;
    #pragma unroll
    for (int k = 0; k < NF_ / 64; ++k) {
        int i = lane + 64 * k;
        f += ws[B_ + 2 * i];
        c += ws[B_ + 2 * i + 1];
    }
    #pragma unroll
    for (int off = 1; off < 64; off <<= 1) {
        llh += __shfl_xor(llh, off, 64);
        f += __shfl_xor(f, off, 64);
        c += __shfl_xor(c, off, 64);
    }
    if (lane == 0) {
        float crf = -(llh * (1.0f / B_));
        float scale = f / fmaxf(c, 1.f);
        scale = fmaxf(scale, 0.1f);
        out[0] = crf * scale;
    }
}

extern "C" void kernel_launch(void* const* d_in, const int* in_sizes, int n_in,
                              void* d_out, int out_size, void* d_ws, size_t ws_size,
                              hipStream_t stream) {
    const float* em = (const float*)d_in[0];
    const int* lab = (const int*)d_in[1];
    const int* msk = (const int*)d_in[2];  // harness stores jnp bool as int32
    const float* trans = (const float*)d_in[3];
    const float* stv = (const float*)d_in[4];
    const float* env = (const float*)d_in[5];
    float* ws = (float*)d_ws;
    float* out = (float*)d_out;

    fcrf_main<<<dim3(B_ + NF_), dim3(64), 0, stream>>>(em, lab, msk, trans, stv, env, ws);
    fcrf_final<<<dim3(1), dim3(64), 0, stream>>>(ws, out);
}

// Round 6
// 372.332 us; speedup vs baseline: 2.0299x; 2.0299x over previous
//
#include <hip/hip_runtime.h>

#define B_ 128
#define T_ 2048
#define K_ 64
#define C_ 8           // chunks per batch
#define S_ 256         // steps per chunk
#define NSCAN (B_*C_)  // 1024 scan waves
#define NF_ 256
#define L2E 1.44269504088896340736f
#define LN2 0.69314718055994530942f

#define POFF 0
#define LOFF (NSCAN*4096)        // per-chunk log-normalizers
#define GOFF (LOFF + NSCAN)      // gold scores per batch
#define LLOFF (GOFF + B_)        // llh per batch
#define FOFF (LLOFF + B_)        // focal partials (2*NF_)

typedef __attribute__((ext_vector_type(4))) unsigned int uint4v;
typedef __attribute__((ext_vector_type(8))) short short8v;
typedef __attribute__((ext_vector_type(16))) float f32x16;
typedef __attribute__((ext_vector_type(4))) float float4v;

__device__ __forceinline__ float rfl_f(float x) {
    return __int_as_float(__builtin_amdgcn_readfirstlane(__float_as_int(x)));
}
// RNE pack two f32 -> b32 of two bf16 (lo = first arg)
__device__ __forceinline__ unsigned pkbf16(float lo, float hi) {
    unsigned r;
    asm volatile("v_cvt_pk_bf16_f32 %0, %1, %2" : "=v"(r) : "v"(lo), "v"(hi));
    return r;
}
__device__ __forceinline__ short8v mk8(unsigned a, unsigned b, unsigned c, unsigned d) {
    uint4v u; u[0] = a; u[1] = b; u[2] = c; u[3] = d;
    return __builtin_bit_cast(short8v, u);
}
__device__ __forceinline__ f32x16 zero16() {
    f32x16 z;
    #pragma unroll
    for (int i = 0; i < 16; ++i) z[i] = 0.f;
    return z;
}

// Kernel A: blocks [0,1024) chunk scans; [1024,1152) gold scores; [1152,1408) focal.
__global__ __launch_bounds__(64, 1) void fcrf_scan(
    const float* __restrict__ em, const int* __restrict__ lab,
    const int* __restrict__ msk, const float* __restrict__ trans,
    const float* __restrict__ stv, const float* __restrict__ env,
    float* __restrict__ ws)
{
    __shared__ float sh[K_ * K_];
    const int lane = threadIdx.x;
    const int blk = blockIdx.x;
    const int h = lane >> 5;
    const int cc = lane & 31;

    if (blk < NSCAN) {
        // ---------- chunk transfer-matrix scan ----------
        const int w = blk, b = w >> 3, c = w & 7;
        const float* emB = em + (size_t)b * T_ * K_;
        const int* labB = lab + (size_t)b * T_;
        const int* mskB = msk + (size_t)b * T_;

        // A-frags: W^T in bf16, A[row=32I+cc][k=16s+8h+j] = exp(trans[k][row])
        unsigned au[2][4][4];
        #pragma unroll
        for (int I = 0; I < 2; ++I)
            #pragma unroll
            for (int s = 0; s < 4; ++s) {
                float wv[8];
                #pragma unroll
                for (int j = 0; j < 8; ++j)
                    wv[j] = __builtin_amdgcn_exp2f(
                        trans[(16*s + 8*h + j) * K_ + 32*I + cc] * L2E);
                #pragma unroll
                for (int p = 0; p < 4; ++p)
                    au[I][s][p] = pkbf16(wv[2*p], wv[2*p+1]);
            }

        // B-frags: state S init = identity. B[k=16s+8h+2p(+1)][col=32J+cc]
        unsigned bu[4][2][4];
        #pragma unroll
        for (int s = 0; s < 4; ++s)
            #pragma unroll
            for (int J = 0; J < 2; ++J)
                #pragma unroll
                for (int p = 0; p < 4; ++p) {
                    int k0 = 16*s + 8*h + 2*p, col = 32*J + cc;
                    unsigned u = 0;
                    if (k0 == col) u |= 0x3F80u;
                    if (k0 + 1 == col) u |= 0x3F800000u;
                    bu[s][J][p] = u;
                }

        float L = 0.f;
        int t = 1 + c * S_;
        float4v er[2][4];
        int lc, mc2;
        {
            int tl = t < T_ ? t : T_ - 1;
            const float4v* ep = (const float4v*)(emB + (size_t)tl * K_);
            #pragma unroll
            for (int I = 0; I < 2; ++I)
                #pragma unroll
                for (int Q = 0; Q < 4; ++Q) er[I][Q] = ep[8*I + 2*Q + h];
            lc = labB[tl]; mc2 = mskB[tl];
        }

        for (int st = 0; st < S_; ++st) {
            // prefetch next step
            int tn = t + 1;
            int tln = tn < T_ ? tn : T_ - 1;
            float4v en[2][4];
            const float4v* epn = (const float4v*)(emB + (size_t)tln * K_);
            #pragma unroll
            for (int I = 0; I < 2; ++I)
                #pragma unroll
                for (int Q = 0; Q < 4; ++Q) en[I][Q] = epn[8*I + 2*Q + h];
            int ln_ = labB[tln], mn_ = mskB[tln];

            bool m = (t < T_) && (lc != -100) && (mc2 != 0);
            if (m) {
                // C = W^T * S   (16 MFMA)
                f32x16 acc[2][2];
                #pragma unroll
                for (int I = 0; I < 2; ++I)
                    #pragma unroll
                    for (int J = 0; J < 2; ++J) acc[I][J] = zero16();
                #pragma unroll
                for (int s = 0; s < 4; ++s) {
                    short8v bs0 = mk8(bu[s][0][0], bu[s][0][1], bu[s][0][2], bu[s][0][3]);
                    short8v bs1 = mk8(bu[s][1][0], bu[s][1][1], bu[s][1][2], bu[s][1][3]);
                    short8v as0 = mk8(au[0][s][0], au[0][s][1], au[0][s][2], au[0][s][3]);
                    short8v as1 = mk8(au[1][s][0], au[1][s][1], au[1][s][2], au[1][s][3]);
                    acc[0][0] = __builtin_amdgcn_mfma_f32_32x32x16_bf16(as0, bs0, acc[0][0], 0, 0, 0);
                    acc[0][1] = __builtin_amdgcn_mfma_f32_32x32x16_bf16(as0, bs1, acc[0][1], 0, 0, 0);
                    acc[1][0] = __builtin_amdgcn_mfma_f32_32x32x16_bf16(as1, bs0, acc[1][0], 0, 0, 0);
                    acc[1][1] = __builtin_amdgcn_mfma_f32_32x32x16_bf16(as1, bs1, acc[1][1], 0, 0, 0);
                }
                // renorm scalar + d-factors
                float c00 = rfl_f(acc[0][0][0]);
                float rho = __builtin_amdgcn_rcpf(c00);
                L += __builtin_amdgcn_logf(c00) * LN2;
                float fr[2][4][4];
                #pragma unroll
                for (int I = 0; I < 2; ++I)
                    #pragma unroll
                    for (int Q = 0; Q < 4; ++Q)
                        #pragma unroll
                        for (int e = 0; e < 4; ++e)
                            fr[I][Q][e] = __builtin_amdgcn_exp2f(er[I][Q][e] * L2E) * rho;
                // S_next = D * C * rho ; repack into B-frags
                #pragma unroll
                for (int I = 0; I < 2; ++I)
                    #pragma unroll
                    for (int J = 0; J < 2; ++J) {
                        float sc[16];
                        #pragma unroll
                        for (int r = 0; r < 16; ++r)
                            sc[r] = acc[I][J][r] * fr[I][r >> 2][r & 3];
                        #pragma unroll
                        for (int sg = 0; sg < 2; ++sg) {
                            const int s = 2*I + sg;
                            const int r0 = 8*sg;
                            unsigned X  = pkbf16(sc[r0+0], sc[r0+1]);
                            unsigned X2 = pkbf16(sc[r0+2], sc[r0+3]);
                            unsigned Y  = pkbf16(sc[r0+4], sc[r0+5]);
                            unsigned Y2 = pkbf16(sc[r0+6], sc[r0+7]);
                            unsigned sX  = (unsigned)__shfl_xor((int)X,  32, 64);
                            unsigned sX2 = (unsigned)__shfl_xor((int)X2, 32, 64);
                            unsigned sY  = (unsigned)__shfl_xor((int)Y,  32, 64);
                            unsigned sY2 = (unsigned)__shfl_xor((int)Y2, 32, 64);
                            bu[s][J][0] = h ? sY  : X;
                            bu[s][J][1] = h ? sY2 : X2;
                            bu[s][J][2] = h ? Y   : sX;
                            bu[s][J][3] = h ? Y2  : sX2;
                        }
                    }
            }
            #pragma unroll
            for (int I = 0; I < 2; ++I)
                #pragma unroll
                for (int Q = 0; Q < 4; ++Q) er[I][Q] = en[I][Q];
            lc = ln_; mc2 = mn_;
            ++t;
        }
        // store G_c (unpack bf16 state) + L
        float* pw = ws + POFF + (size_t)w * 4096;
        #pragma unroll
        for (int s = 0; s < 4; ++s)
            #pragma unroll
            for (int J = 0; J < 2; ++J)
                #pragma unroll
                for (int p = 0; p < 4; ++p) {
                    unsigned u = bu[s][J][p];
                    int k0 = 16*s + 8*h + 2*p, col = 32*J + cc;
                    pw[k0 * 64 + col] = __uint_as_float(u << 16);
                    pw[(k0 + 1) * 64 + col] = __uint_as_float(u & 0xFFFF0000u);
                }
        if (lane == 0) ws[LOFF + w] = L;
    } else if (blk < NSCAN + B_) {
        // ---------- gold-path score (parallel over t, fast path all-valid) ----------
        const int b = blk - NSCAN;
        const int* labB = lab + (size_t)b * T_;
        const int* mskB = msk + (size_t)b * T_;
        for (int i = 0; i < K_; ++i) sh[i * K_ + lane] = trans[i * K_ + lane];
        __syncthreads();
        float sacc = 0.f;
        int carry = 0;
        for (int it = 0; it < T_ / 64; ++it) {
            int tt = it * 64 + lane;
            int lb = labB[tt], mk = mskB[tt];
            int tg = (lb == -100) ? 0 : lb;
            int vm = (lb != -100) && (mk != 0);
            unsigned long long bal = __ballot(vm || tt == 0);
            if (bal == ~0ull) {
                int prev = __shfl_up(tg, 1, 64);
                if (lane == 0) prev = carry;
                float term;
                if (tt == 0)
                    term = stv[tg] + em[(size_t)b * T_ * K_ + tg];
                else
                    term = vm ? (sh[prev * K_ + tg] + em[((size_t)b * T_ + tt) * K_ + tg]) : 0.f;
                sacc += term;
                carry = __builtin_amdgcn_readlane(tg, 63);
            } else {
                int cl = carry;
                float sl = 0.f;
                if (lane == 0) {
                    for (int u = 0; u < 64; ++u) {
                        int t2 = it * 64 + u;
                        int lb2 = labB[t2], mk2 = mskB[t2];
                        int tg2 = (lb2 == -100) ? 0 : lb2;
                        int vm2 = (lb2 != -100) && (mk2 != 0);
                        if (t2 == 0) { sl += stv[tg2] + em[(size_t)b * T_ * K_ + tg2]; cl = tg2; }
                        else if (vm2) { sl += sh[cl * K_ + tg2] + em[((size_t)b * T_ + t2) * K_ + tg2]; cl = tg2; }
                    }
                }
                sacc += sl;
                carry = __builtin_amdgcn_readlane(cl, 0);
            }
        }
        if (lane == 0) sacc += env[carry];
        #pragma unroll
        for (int off = 1; off < 64; off <<= 1) sacc += __shfl_xor(sacc, off, 64);
        if (lane == 0) ws[GOFF + b] = sacc;
    } else {
        // ---------- focal-scale partials ----------
        const int fb = blk - NSCAN - B_;
        const float4* em4 = (const float4*)em;
        const int sub = lane >> 4;
        const int cg = lane & 15;
        float facc = 0.f, cacc = 0.f;
        const int base = fb * (B_ * T_ / NF_);
        for (int it = 0; it < (B_ * T_ / NF_) / 4; ++it) {
            int row = base + it * 4 + sub;
            float4 v = em4[row * (K_ / 4) + cg];
            int lb = lab[row];
            int vm = (lb != -100) & (msk[row] != 0);
            int tg = (lb == -100) ? 0 : lb;
            float mx = fmaxf(fmaxf(v.x, v.y), fmaxf(v.z, v.w));
            #pragma unroll
            for (int off = 1; off < 16; off <<= 1) mx = fmaxf(mx, __shfl_xor(mx, off, 64));
            float se = __builtin_amdgcn_exp2f((v.x - mx) * L2E)
                     + __builtin_amdgcn_exp2f((v.y - mx) * L2E)
                     + __builtin_amdgcn_exp2f((v.z - mx) * L2E)
                     + __builtin_amdgcn_exp2f((v.w - mx) * L2E);
            int c0 = cg * 4;
            float sel = ((c0 + 0 == tg) ? v.x : 0.f) + ((c0 + 1 == tg) ? v.y : 0.f)
                      + ((c0 + 2 == tg) ? v.z : 0.f) + ((c0 + 3 == tg) ? v.w : 0.f);
            #pragma unroll
            for (int off = 1; off < 16; off <<= 1) {
                se += __shfl_xor(se, off, 64);
                sel += __shfl_xor(sel, off, 64);
            }
            float p = __builtin_amdgcn_exp2f((sel - mx) * L2E) / se;
            float fw = (1.f - p) * (1.f - p);
            if (cg == 0) {
                facc += vm ? fw : 0.f;
                cacc += vm ? 1.f : 0.f;
            }
        }
        #pragma unroll
        for (int off = 1; off < 64; off <<= 1) {
            facc += __shfl_xor(facc, off, 64);
            cacc += __shfl_xor(cacc, off, 64);
        }
        if (lane == 0) {
            ws[FOFF + 2 * fb] = facc;
            ws[FOFF + 2 * fb + 1] = cacc;
        }
    }
}

// Kernel B: per-batch combine: alpha0 through 8 chunk matrices -> logZ -> llh
__global__ __launch_bounds__(64) void fcrf_combine(
    const float* __restrict__ em, const float* __restrict__ stv,
    const float* __restrict__ env, float* __restrict__ ws)
{
    __shared__ __align__(16) float vb[64];
    const int b = blockIdx.x, j = threadIdx.x;
    float a = stv[j] + em[(size_t)b * T_ * K_ + j];
    float a0 = rfl_f(a);
    float Lv = a0;
    float v = __builtin_amdgcn_exp2f((a - a0) * L2E);
    for (int c = 0; c < C_; ++c) {
        vb[j] = v;
        __syncthreads();
        const float4v* gp = (const float4v*)(ws + POFF + (size_t)(b * C_ + c) * 4096 + j * 64);
        const float4v* vp = (const float4v*)vb;
        float s0 = 0.f, s1 = 0.f, s2 = 0.f, s3 = 0.f;
        #pragma unroll
        for (int q = 0; q < 16; ++q) {
            float4v g = gp[q];
            float4v x = vp[q];
            s0 = fmaf(g[0], x[0], s0);
            s1 = fmaf(g[1], x[1], s1);
            s2 = fmaf(g[2], x[2], s2);
            s3 = fmaf(g[3], x[3], s3);
        }
        float out = (s0 + s1) + (s2 + s3);
        float o0 = rfl_f(out);
        v = out * __builtin_amdgcn_rcpf(o0);
        Lv += __builtin_amdgcn_logf(o0) * LN2 + ws[LOFF + b * C_ + c];
        __syncthreads();
    }
    float x = v * __builtin_amdgcn_exp2f(env[j] * L2E);
    #pragma unroll
    for (int off = 1; off < 64; off <<= 1) x += __shfl_xor(x, off, 64);
    float logZ = Lv + __builtin_amdgcn_logf(x) * LN2;
    if (j == 0) ws[LLOFF + b] = ws[GOFF + b] - logZ;
}

__global__ __launch_bounds__(64) void fcrf_final(const float* __restrict__ ws,
                                                 float* __restrict__ out)
{
    const int lane = threadIdx.x;
    float llh = ws[LLOFF + lane] + ws[LLOFF + 64 + lane];
    float f = 0.f, c = 0.f;
    #pragma unroll
    for (int k = 0; k < NF_ / 64; ++k) {
        int i = lane + 64 * k;
        f += ws[FOFF + 2 * i];
        c += ws[FOFF + 2 * i + 1];
    }
    #pragma unroll
    for (int off = 1; off < 64; off <<= 1) {
        llh += __shfl_xor(llh, off, 64);
        f += __shfl_xor(f, off, 64);
        c += __shfl_xor(c, off, 64);
    }
    if (lane == 0) {
        float crf = -(llh * (1.0f / B_));
        float scale = f / fmaxf(c, 1.f);
        scale = fmaxf(scale, 0.1f);
        out[0] = crf * scale;
    }
}

extern "C" void kernel_launch(void* const* d_in, const int* in_sizes, int n_in,
                              void* d_out, int out_size, void* d_ws, size_t ws_size,
                              hipStream_t stream) {
    const float* em = (const float*)d_in[0];
    const int* lab = (const int*)d_in[1];
    const int* msk = (const int*)d_in[2];  // jnp bool stored as int32
    const float* trans = (const float*)d_in[3];
    const float* stv = (const float*)d_in[4];
    const float* env = (const float*)d_in[5];
    float* ws = (float*)d_ws;
    float* out = (float*)d_out;

    fcrf_scan<<<dim3(NSCAN + B_ + NF_), dim3(64), 0, stream>>>(em, lab, msk, trans, stv, env, ws);
    fcrf_combine<<<dim3(B_), dim3(64), 0, stream>>>(em, stv, env, ws);
    fcrf_final<<<dim3(1), dim3(64), 0, stream>>>(ws, out);
}